// Round 7
// baseline (78.986 us; speedup 1.0000x reference)
//
#include <hip/hip_runtime.h>
#include <stdint.h>
#include <stddef.h>

typedef __attribute__((ext_vector_type(8))) short short8;
typedef __attribute__((ext_vector_type(4))) float f32x4;

__device__ inline unsigned short f2bf(float x) {
    unsigned u = __float_as_uint(x);
    unsigned r = (u + 0x7fffu + ((u >> 16) & 1u)) >> 16;
    return (unsigned short)r;
}

// ---------------- K12: node = mean(tf) fused with pi/pj projection ----------
// 512 blocks x 512 threads. Block owns 8 node-rows = 1 MB contiguous tf.
// Phase 1: stream-reduce tf -> node tile in LDS (bf16, pitch 136).
// Phase 2: MFMA [8x128] @ W1^T[256x128] -> pi (+b1) and pj.
__global__ __launch_bounds__(512) void k12_mean_proj(const float* __restrict__ tf,
                                                     const float* __restrict__ W1,
                                                     const float* __restrict__ b1,
                                                     float* __restrict__ pi,
                                                     float* __restrict__ pj) {
    const int LP = 136;
    __shared__ unsigned short A_lds[16 * LP];   // rows 0..7 data, 8..15 zero pad
    __shared__ unsigned short BT[256 * LP];     // BT[c][k] = W1[(c>>7)*128+k][c&127]
    __shared__ float b1s[128];

    int tid = threadIdx.x;
    int blk = blockIdx.x;       // 0..511
    int R0 = blk * 8;           // first node row

    // zero A (pad rows 8..15 must be clean; rows 0..7 get overwritten)
    for (int idx = tid; idx < 16 * LP; idx += 512) A_lds[idx] = 0;

    // Stage BT: thread t -> out-col c = t&255, k-half kh = t>>8.
    // For fixed e, lanes read 128 consecutive floats of a W1 row (coalesced).
    {
        int c = tid & 255;
        int kh = tid >> 8;
        int n = c & 127, hf = c >> 7;
        const float* Wb = W1 + (size_t)hf * 128 * 128 + n;
#pragma unroll
        for (int g = 0; g < 8; ++g) {
            int kb = kh * 64 + g * 8;
            short8 pk;
#pragma unroll
            for (int e = 0; e < 8; ++e) pk[e] = (short)f2bf(Wb[(size_t)(kb + e) * 128]);
            *reinterpret_cast<short8*>(&BT[c * LP + kb]) = pk;
        }
    }
    if (tid < 128) b1s[tid] = b1[tid];

    // Phase 1: mean over T. Per wave: 64 row-pairs (8 iters x 8 pairs).
    int w = tid >> 6;
    int l = tid & 63;
    int half = l >> 5;
    int c32 = l & 31;
    const float4* tf4 = reinterpret_cast<const float4*>(tf);
    size_t bb = (size_t)blk * 32768;   // float4 base of this block's 1 MB

    for (int it = 0; it < 8; ++it) {
        float4 v[8];
#pragma unroll
        for (int k = 0; k < 8; ++k) {
            int rp = w * 64 + it * 8 + k;
            v[k] = tf4[bb + (size_t)rp * 64 + l];
        }
        float s[8];
#pragma unroll
        for (int k = 0; k < 8; ++k) s[k] = (v[k].x + v[k].y) + (v[k].z + v[k].w);
#pragma unroll
        for (int m = 1; m <= 16; m <<= 1) {
#pragma unroll
            for (int k = 0; k < 8; ++k) s[k] += __shfl_xor(s[k], m);
        }
        if (c32 == 0) {
#pragma unroll
            for (int k = 0; k < 8; ++k) {
                int tr = (w * 64 + it * 8 + k) * 2 + half;   // 0..1023
                A_lds[(tr >> 7) * LP + (tr & 127)] = f2bf(s[k] * (1.0f / 128.0f));
            }
        }
    }
    __syncthreads();

    // Phase 2: wave w -> out cols [w*32, w*32+32), rows 0..7 (lg<2).
    int lr = l & 15, lg = l >> 4;
    f32x4 acc[2] = {{0, 0, 0, 0}, {0, 0, 0, 0}};
#pragma unroll
    for (int ks = 0; ks < 4; ++ks) {
        int kb = ks * 32 + lg * 8;
        short8 af = *reinterpret_cast<const short8*>(&A_lds[lr * LP + kb]);
#pragma unroll
        for (int nt = 0; nt < 2; ++nt) {
            short8 bf = *reinterpret_cast<const short8*>(&BT[(w * 32 + nt * 16 + lr) * LP + kb]);
            acc[nt] = __builtin_amdgcn_mfma_f32_16x16x32_bf16(af, bf, acc[nt], 0, 0, 0);
        }
    }
    if (lg < 2) {
#pragma unroll
        for (int nt = 0; nt < 2; ++nt) {
            int col = w * 32 + nt * 16 + lr;
#pragma unroll
            for (int r = 0; r < 4; ++r) {
                int row = R0 + lg * 4 + r;
                if (col < 128) pi[(size_t)row * 128 + col] = acc[nt][r] + b1s[col];
                else           pj[(size_t)row * 128 + (col - 128)] = acc[nt][r];
            }
        }
    }
}

// ---------------- K3: pairwise MLP via MFMA ----------------
// block = (b, i-tile of 4). 256 threads = 4 waves.
// ALL 4 pi rows prefetched to LDS at block start -> loop body is LDS-only.
__global__ __launch_bounds__(256) void k3_mlp(const float* __restrict__ pi,
                                              const float* __restrict__ pj,
                                              const float* __restrict__ W2,
                                              const float* __restrict__ b2,
                                              const float* __restrict__ W3,
                                              const float* __restrict__ b3,
                                              float* __restrict__ F) {
    const int LDA = 136;
    __shared__ unsigned short A_lds[64 * LDA];
    __shared__ unsigned short W2T[64 * LDA];
    __shared__ float pipb4[4][128];
    __shared__ float b2s[64], w3s[64];

    int tid = threadIdx.x;
    int b = blockIdx.x >> 4;
    int it = blockIdx.x & 15;
    int i0 = it * 4;
    int jt = tid >> 2;
    int kq = tid & 3;

    float pjreg[32];
    {
        const float* src = pj + ((size_t)(b * 64 + jt) * 128 + kq * 32);
#pragma unroll
        for (int e = 0; e < 8; ++e) {
            float4 v = reinterpret_cast<const float4*>(src)[e];
            pjreg[e * 4 + 0] = v.x;
            pjreg[e * 4 + 1] = v.y;
            pjreg[e * 4 + 2] = v.z;
            pjreg[e * 4 + 3] = v.w;
        }
    }
    if (tid < 128) {
        int row = tid >> 5;
        int c4 = tid & 31;
        float4 v = reinterpret_cast<const float4*>(pi + ((size_t)(b * 64 + i0 + row) * 128))[c4];
        reinterpret_cast<float4*>(&pipb4[row][0])[c4] = v;
    }
    {
        int m = jt;
        for (int e = 0; e < 32; ++e) {
            int k = kq * 32 + e;
            W2T[m * LDA + k] = f2bf(W2[(size_t)k * 64 + m]);
        }
    }
    if (tid < 64) {
        b2s[tid] = b2[tid];
        w3s[tid] = W3[tid];
    }
    float b3v = b3[0];
    __syncthreads();

    int w = tid >> 6;
    int l = tid & 63;
    int lr = l & 15;
    int lg = l >> 4;

    for (int il = 0; il < 4; ++il) {
        {
            unsigned* dst = reinterpret_cast<unsigned*>(&A_lds[jt * LDA + kq * 32]);
#pragma unroll
            for (int e2 = 0; e2 < 16; ++e2) {
                float a0 = pipb4[il][kq * 32 + e2 * 2 + 0] + pjreg[e2 * 2 + 0];
                float a1 = pipb4[il][kq * 32 + e2 * 2 + 1] + pjreg[e2 * 2 + 1];
                a0 = fmaxf(a0, 0.0f);
                a1 = fmaxf(a1, 0.0f);
                dst[e2] = (unsigned)f2bf(a0) | ((unsigned)f2bf(a1) << 16);
            }
        }
        __syncthreads();
        f32x4 acc0 = {0.f, 0.f, 0.f, 0.f};
        f32x4 acc1 = {0.f, 0.f, 0.f, 0.f};
        f32x4 acc2 = {0.f, 0.f, 0.f, 0.f};
        f32x4 acc3 = {0.f, 0.f, 0.f, 0.f};
#pragma unroll
        for (int ks = 0; ks < 4; ++ks) {
            int kb = ks * 32 + lg * 8;
            short8 afrag = *reinterpret_cast<const short8*>(&A_lds[(w * 16 + lr) * LDA + kb]);
            short8 b0 = *reinterpret_cast<const short8*>(&W2T[(0 * 16 + lr) * LDA + kb]);
            short8 b1f = *reinterpret_cast<const short8*>(&W2T[(1 * 16 + lr) * LDA + kb]);
            short8 b2f = *reinterpret_cast<const short8*>(&W2T[(2 * 16 + lr) * LDA + kb]);
            short8 b3f = *reinterpret_cast<const short8*>(&W2T[(3 * 16 + lr) * LDA + kb]);
            acc0 = __builtin_amdgcn_mfma_f32_16x16x32_bf16(afrag, b0, acc0, 0, 0, 0);
            acc1 = __builtin_amdgcn_mfma_f32_16x16x32_bf16(afrag, b1f, acc1, 0, 0, 0);
            acc2 = __builtin_amdgcn_mfma_f32_16x16x32_bf16(afrag, b2f, acc2, 0, 0, 0);
            acc3 = __builtin_amdgcn_mfma_f32_16x16x32_bf16(afrag, b3f, acc3, 0, 0, 0);
        }
        float part[4] = {0.f, 0.f, 0.f, 0.f};
#pragma unroll
        for (int mt = 0; mt < 4; ++mt) {
            int m = mt * 16 + lr;
            float w3 = w3s[m];
            float bb = b2s[m];
            f32x4 a = (mt == 0) ? acc0 : (mt == 1) ? acc1 : (mt == 2) ? acc2 : acc3;
#pragma unroll
            for (int r = 0; r < 4; ++r) {
                float h = fmaxf(a[r] + bb, 0.0f);
                part[r] += h * w3;
            }
        }
#pragma unroll
        for (int r = 0; r < 4; ++r) {
            part[r] += __shfl_xor(part[r], 1);
            part[r] += __shfl_xor(part[r], 2);
            part[r] += __shfl_xor(part[r], 4);
            part[r] += __shfl_xor(part[r], 8);
        }
        if (lr == 0) {
#pragma unroll
            for (int r = 0; r < 4; ++r) {
                int j = w * 16 + lg * 4 + r;
                F[((size_t)b * 64 + i0 + il) * 64 + j] = part[r] + b3v;
            }
        }
        __syncthreads();
    }
}

// ---------------- K4: symmetrize + eye + row-normalize ----------------
__global__ __launch_bounds__(256) void k4_final(const float* __restrict__ F,
                                                const float* __restrict__ ap,
                                                float* __restrict__ out) {
    __shared__ float s[64][65];
    __shared__ float rs[64];
    int b = blockIdx.x;
    int tid = threadIdx.x;
    for (int idx = tid; idx < 4096; idx += 256) {
        int i = idx >> 6, j = idx & 63;
        float f_ij = F[(size_t)b * 4096 + idx];
        float f_ji = F[(size_t)b * 4096 + j * 64 + i];
        float a_ij = ap[idx];
        float a_ji = ap[j * 64 + i];
        float v = 0.25f * (a_ij + a_ji) + 0.25f * (f_ij + f_ji);
        v = fmaxf(v, 0.0f);
        if (i == j) v += 1.0f;
        s[i][j] = v;
    }
    __syncthreads();
    int wv = tid >> 6, ln = tid & 63;
    for (int i = wv * 16; i < wv * 16 + 16; ++i) {
        float v = s[i][ln];
        v += __shfl_xor(v, 1);
        v += __shfl_xor(v, 2);
        v += __shfl_xor(v, 4);
        v += __shfl_xor(v, 8);
        v += __shfl_xor(v, 16);
        v += __shfl_xor(v, 32);
        if (ln == 0) rs[i] = v;
    }
    __syncthreads();
    for (int idx = tid; idx < 4096; idx += 256) {
        int i = idx >> 6, j = idx & 63;
        out[(size_t)b * 4096 + idx] = s[i][j] / (rs[i] + 1e-8f);
    }
}

extern "C" void kernel_launch(void* const* d_in, const int* in_sizes, int n_in,
                              void* d_out, int out_size, void* d_ws, size_t ws_size,
                              hipStream_t stream) {
    const float* tf = (const float*)d_in[0];
    const float* ap = (const float*)d_in[1];
    const float* W1 = (const float*)d_in[2];
    const float* b1 = (const float*)d_in[3];
    const float* W2 = (const float*)d_in[4];
    const float* b2 = (const float*)d_in[5];
    const float* W3 = (const float*)d_in[6];
    const float* b3 = (const float*)d_in[7];
    float* out = (float*)d_out;

    char* ws = (char*)d_ws;
    float* pi   = (float*)(ws + (size_t)(2 << 20));      // 2 MB (pi + b1)
    float* pj   = (float*)(ws + (size_t)(4 << 20));      // 2 MB
    float* F    = (float*)(ws + (size_t)(6 << 20));      // 1 MB

    k12_mean_proj<<<512, 512, 0, stream>>>(tf, W1, b1, pi, pj);
    k3_mlp<<<1024, 256, 0, stream>>>(pi, pj, W2, b2, W3, b3, F);
    k4_final<<<64, 256, 0, stream>>>(F, ap, out);
}

// Round 8
// 77.090 us; speedup vs baseline: 1.0246x; 1.0246x over previous
//
#include <hip/hip_runtime.h>
#include <stdint.h>
#include <stddef.h>

typedef __attribute__((ext_vector_type(8))) short short8;
typedef __attribute__((ext_vector_type(4))) float f32x4;

__device__ inline unsigned short f2bf(float x) {
    unsigned u = __float_as_uint(x);
    unsigned r = (u + 0x7fffu + ((u >> 16) & 1u)) >> 16;
    return (unsigned short)r;
}

// ---------------- K1: node = mean(tf, axis=-1) ----------------
// 8192 blocks x 4 waves, 8 row-pairs per wave; 8 independent 1KB nt-loads in
// flight per wave; interleaved shuffle chains.
__global__ __launch_bounds__(256) void k1_mean(const float* __restrict__ tf,
                                               float* __restrict__ node) {
    int wave = (blockIdx.x * blockDim.x + threadIdx.x) >> 6;  // 0..32767
    int lane = threadIdx.x & 63;
    int half = lane >> 5;
    int c = lane & 31;
    const f32x4* tf4 = reinterpret_cast<const f32x4*>(tf);
    size_t base = (size_t)wave * 8 * 64;

    f32x4 v[8];
#pragma unroll
    for (int k = 0; k < 8; ++k) v[k] = __builtin_nontemporal_load(&tf4[base + (size_t)k * 64 + lane]);

    float s[8];
#pragma unroll
    for (int k = 0; k < 8; ++k) s[k] = (v[k][0] + v[k][1]) + (v[k][2] + v[k][3]);
#pragma unroll
    for (int m = 1; m <= 16; m <<= 1) {
#pragma unroll
        for (int k = 0; k < 8; ++k) s[k] += __shfl_xor(s[k], m);
    }
    if (c == 0) {
#pragma unroll
        for (int k = 0; k < 8; ++k) {
            int rp = wave * 8 + k;
            node[(size_t)rp * 2 + half] = s[k] * (1.0f / 128.0f);
        }
    }
}

// ---------------- K2: pi = node@Wi + b1, pj = node@Wj (MFMA) ----------------
__global__ __launch_bounds__(256) void k2_proj(const float* __restrict__ node,
                                               const float* __restrict__ W1,
                                               const float* __restrict__ b1,
                                               float* __restrict__ pi,
                                               float* __restrict__ pj) {
    const int LP = 136;
    __shared__ unsigned short A_lds[32 * LP];
    __shared__ unsigned short BT[128 * LP];
    __shared__ float b1s[128];

    int tid = threadIdx.x;
    int rblk = blockIdx.x >> 1;
    int half = blockIdx.x & 1;
    int r0 = rblk * 32;

    {
        int row = tid >> 3;
        int c0 = (tid & 7) * 16;
        const float4* src = reinterpret_cast<const float4*>(node + (size_t)(r0 + row) * 128 + c0);
        short8 pk[2];
#pragma unroll
        for (int q = 0; q < 2; ++q) {
            float4 va = src[q * 2 + 0];
            float4 vb = src[q * 2 + 1];
            pk[q][0] = (short)f2bf(va.x); pk[q][1] = (short)f2bf(va.y);
            pk[q][2] = (short)f2bf(va.z); pk[q][3] = (short)f2bf(va.w);
            pk[q][4] = (short)f2bf(vb.x); pk[q][5] = (short)f2bf(vb.y);
            pk[q][6] = (short)f2bf(vb.z); pk[q][7] = (short)f2bf(vb.w);
        }
        short8* dst = reinterpret_cast<short8*>(&A_lds[row * LP + c0]);
        dst[0] = pk[0];
        dst[1] = pk[1];
    }
    {
        int n = tid & 127;
        int kh = tid >> 7;
        const float* Wbase = W1 + (size_t)half * 128 * 128 + n;
#pragma unroll
        for (int g = 0; g < 8; ++g) {
            int kb = kh * 64 + g * 8;
            short8 pk;
#pragma unroll
            for (int e = 0; e < 8; ++e) pk[e] = (short)f2bf(Wbase[(size_t)(kb + e) * 128]);
            *reinterpret_cast<short8*>(&BT[n * LP + kb]) = pk;
        }
    }
    if (tid < 128) b1s[tid] = b1[tid];
    __syncthreads();

    int w = tid >> 6;
    int l = tid & 63;
    int lr = l & 15;
    int lg = l >> 4;
    int rt = w & 1;
    int ch = w >> 1;

    f32x4 acc[4] = {{0,0,0,0},{0,0,0,0},{0,0,0,0},{0,0,0,0}};
#pragma unroll
    for (int ks = 0; ks < 4; ++ks) {
        int kb = ks * 32 + lg * 8;
        short8 afrag = *reinterpret_cast<const short8*>(&A_lds[(rt * 16 + lr) * LP + kb]);
#pragma unroll
        for (int nt = 0; nt < 4; ++nt) {
            short8 bfrag = *reinterpret_cast<const short8*>(&BT[(ch * 64 + nt * 16 + lr) * LP + kb]);
            acc[nt] = __builtin_amdgcn_mfma_f32_16x16x32_bf16(afrag, bfrag, acc[nt], 0, 0, 0);
        }
    }
    float* out = half ? pj : pi;
#pragma unroll
    for (int nt = 0; nt < 4; ++nt) {
        int col = ch * 64 + nt * 16 + lr;
        float bias = half ? 0.0f : b1s[col];
#pragma unroll
        for (int r = 0; r < 4; ++r) {
            int row = r0 + rt * 16 + lg * 4 + r;
            out[(size_t)row * 128 + col] = acc[nt][r] + bias;
        }
    }
}

// ---------------- K3: pairwise MLP via MFMA ----------------
// block = (b, i-tile of 4). 256 threads = 4 waves.
// ALL 4 pi rows prefetched to LDS at block start -> loop body is LDS-only.
__global__ __launch_bounds__(256) void k3_mlp(const float* __restrict__ pi,
                                              const float* __restrict__ pj,
                                              const float* __restrict__ W2,
                                              const float* __restrict__ b2,
                                              const float* __restrict__ W3,
                                              const float* __restrict__ b3,
                                              float* __restrict__ F) {
    const int LDA = 136;
    __shared__ unsigned short A_lds[64 * LDA];
    __shared__ unsigned short W2T[64 * LDA];
    __shared__ float pipb4[4][128];
    __shared__ float b2s[64], w3s[64];

    int tid = threadIdx.x;
    int b = blockIdx.x >> 4;
    int it = blockIdx.x & 15;
    int i0 = it * 4;
    int jt = tid >> 2;
    int kq = tid & 3;

    float pjreg[32];
    {
        const float* src = pj + ((size_t)(b * 64 + jt) * 128 + kq * 32);
#pragma unroll
        for (int e = 0; e < 8; ++e) {
            float4 v = reinterpret_cast<const float4*>(src)[e];
            pjreg[e * 4 + 0] = v.x;
            pjreg[e * 4 + 1] = v.y;
            pjreg[e * 4 + 2] = v.z;
            pjreg[e * 4 + 3] = v.w;
        }
    }
    if (tid < 128) {
        int row = tid >> 5;
        int c4 = tid & 31;
        float4 v = reinterpret_cast<const float4*>(pi + ((size_t)(b * 64 + i0 + row) * 128))[c4];
        reinterpret_cast<float4*>(&pipb4[row][0])[c4] = v;
    }
    {
        int m = jt;
        for (int e = 0; e < 32; ++e) {
            int k = kq * 32 + e;
            W2T[m * LDA + k] = f2bf(W2[(size_t)k * 64 + m]);
        }
    }
    if (tid < 64) {
        b2s[tid] = b2[tid];
        w3s[tid] = W3[tid];
    }
    float b3v = b3[0];
    __syncthreads();

    int w = tid >> 6;
    int l = tid & 63;
    int lr = l & 15;
    int lg = l >> 4;

    for (int il = 0; il < 4; ++il) {
        {
            unsigned* dst = reinterpret_cast<unsigned*>(&A_lds[jt * LDA + kq * 32]);
#pragma unroll
            for (int e2 = 0; e2 < 16; ++e2) {
                float a0 = pipb4[il][kq * 32 + e2 * 2 + 0] + pjreg[e2 * 2 + 0];
                float a1 = pipb4[il][kq * 32 + e2 * 2 + 1] + pjreg[e2 * 2 + 1];
                a0 = fmaxf(a0, 0.0f);
                a1 = fmaxf(a1, 0.0f);
                dst[e2] = (unsigned)f2bf(a0) | ((unsigned)f2bf(a1) << 16);
            }
        }
        __syncthreads();
        f32x4 acc0 = {0.f, 0.f, 0.f, 0.f};
        f32x4 acc1 = {0.f, 0.f, 0.f, 0.f};
        f32x4 acc2 = {0.f, 0.f, 0.f, 0.f};
        f32x4 acc3 = {0.f, 0.f, 0.f, 0.f};
#pragma unroll
        for (int ks = 0; ks < 4; ++ks) {
            int kb = ks * 32 + lg * 8;
            short8 afrag = *reinterpret_cast<const short8*>(&A_lds[(w * 16 + lr) * LDA + kb]);
            short8 b0 = *reinterpret_cast<const short8*>(&W2T[(0 * 16 + lr) * LDA + kb]);
            short8 b1f = *reinterpret_cast<const short8*>(&W2T[(1 * 16 + lr) * LDA + kb]);
            short8 b2f = *reinterpret_cast<const short8*>(&W2T[(2 * 16 + lr) * LDA + kb]);
            short8 b3f = *reinterpret_cast<const short8*>(&W2T[(3 * 16 + lr) * LDA + kb]);
            acc0 = __builtin_amdgcn_mfma_f32_16x16x32_bf16(afrag, b0, acc0, 0, 0, 0);
            acc1 = __builtin_amdgcn_mfma_f32_16x16x32_bf16(afrag, b1f, acc1, 0, 0, 0);
            acc2 = __builtin_amdgcn_mfma_f32_16x16x32_bf16(afrag, b2f, acc2, 0, 0, 0);
            acc3 = __builtin_amdgcn_mfma_f32_16x16x32_bf16(afrag, b3f, acc3, 0, 0, 0);
        }
        float part[4] = {0.f, 0.f, 0.f, 0.f};
#pragma unroll
        for (int mt = 0; mt < 4; ++mt) {
            int m = mt * 16 + lr;
            float w3 = w3s[m];
            float bb = b2s[m];
            f32x4 a = (mt == 0) ? acc0 : (mt == 1) ? acc1 : (mt == 2) ? acc2 : acc3;
#pragma unroll
            for (int r = 0; r < 4; ++r) {
                float h = fmaxf(a[r] + bb, 0.0f);
                part[r] += h * w3;
            }
        }
#pragma unroll
        for (int r = 0; r < 4; ++r) {
            part[r] += __shfl_xor(part[r], 1);
            part[r] += __shfl_xor(part[r], 2);
            part[r] += __shfl_xor(part[r], 4);
            part[r] += __shfl_xor(part[r], 8);
        }
        if (lr == 0) {
#pragma unroll
            for (int r = 0; r < 4; ++r) {
                int j = w * 16 + lg * 4 + r;
                F[((size_t)b * 64 + i0 + il) * 64 + j] = part[r] + b3v;
            }
        }
        __syncthreads();
    }
}

// ---------------- K4: symmetrize + eye + row-normalize ----------------
// ap is symmetric by construction => 0.25*(a_ij+a_ji) == 0.5*a_ij exactly.
// F transpose served from LDS; row-sum via full xor-reduce broadcast.
__global__ __launch_bounds__(256) void k4_final(const float* __restrict__ F,
                                                const float* __restrict__ ap,
                                                float* __restrict__ out) {
    __shared__ float s[64][65];
    int b = blockIdx.x;
    int tid = threadIdx.x;
    for (int idx = tid; idx < 4096; idx += 256) {
        s[idx >> 6][idx & 63] = F[(size_t)b * 4096 + idx];
    }
    __syncthreads();
    int w = tid >> 6, lane = tid & 63;
#pragma unroll
    for (int itr = 0; itr < 16; ++itr) {
        int i = w + 4 * itr;
        float a_ij = ap[i * 64 + lane];                       // coalesced
        float v = 0.5f * a_ij + 0.25f * (s[i][lane] + s[lane][i]);
        v = fmaxf(v, 0.0f);
        if (i == lane) v += 1.0f;
        float sum = v;
        sum += __shfl_xor(sum, 1);
        sum += __shfl_xor(sum, 2);
        sum += __shfl_xor(sum, 4);
        sum += __shfl_xor(sum, 8);
        sum += __shfl_xor(sum, 16);
        sum += __shfl_xor(sum, 32);
        out[(size_t)b * 4096 + i * 64 + lane] = v / (sum + 1e-8f);
    }
}

extern "C" void kernel_launch(void* const* d_in, const int* in_sizes, int n_in,
                              void* d_out, int out_size, void* d_ws, size_t ws_size,
                              hipStream_t stream) {
    const float* tf = (const float*)d_in[0];
    const float* ap = (const float*)d_in[1];
    const float* W1 = (const float*)d_in[2];
    const float* b1 = (const float*)d_in[3];
    const float* W2 = (const float*)d_in[4];
    const float* b2 = (const float*)d_in[5];
    const float* W3 = (const float*)d_in[6];
    const float* b3 = (const float*)d_in[7];
    float* out = (float*)d_out;

    char* ws = (char*)d_ws;
    float* node = (float*)(ws);                          // 2 MB
    float* pi   = (float*)(ws + (size_t)(2 << 20));      // 2 MB (pi + b1)
    float* pj   = (float*)(ws + (size_t)(4 << 20));      // 2 MB
    float* F    = (float*)(ws + (size_t)(6 << 20));      // 1 MB

    k1_mean<<<8192, 256, 0, stream>>>(tf, node);
    k2_proj<<<256, 256, 0, stream>>>(node, W1, b1, pi, pj);
    k3_mlp<<<1024, 256, 0, stream>>>(pi, pj, W2, b2, W3, b3, F);
    k4_final<<<64, 256, 0, stream>>>(F, ap, out);
}